// Round 12
// baseline (5767.581 us; speedup 1.0000x reference)
//
#include <hip/hip_runtime.h>
#include <stdint.h>

// Problem constants (from reference)
#define S_WORDS 2048
#define LMAX    16
#define CE      256
#define WE      512
#define HDIM    1024
#define GC      1024   // 4*CE
#define GW      4096   // 4*HDIM
#define KW      768    // WE + CE
#define NWG_RNN  128   // recurrence WGs: 8 units each, 1 unit per wave
#define NWB_CHAR 64    // char producer blocks; each runs 4 groups sequentially
#define NPASS    4     // groups per char block (low groups first)
#define NWB_WIN  512   // wordin producer blocks (2 per 8-row group)
#define NMIR    4      // ring mirrors
#define RING_U64 (3 * HDIM)   // u64 per mirror (3 slots x 1024)

// Workspace layout (bytes) — high-water 50,331,648 (48 MiB).
// WT2c aliases in_gates rows 1920..2047 (2 MiB tail). Writers of those rows
// are wordin groups 240..255 only, and they gate on char_all==256 (all char
// groups done reading weights). Ring + flags live in the old WT2c region.
// prep_c/prep_w run as PRIOR dispatches -> weight visibility via kernel-
// boundary ordering.
#define IN_GATES_OFF 0                       // 2048*4096 fp32 = 33554432
#define WT2C_OFF     31457280                // in_gates rows 1920.. (gated alias)
#define LAST_OFF     33554432                // 2048*256 fp32 = 2097152
#define RING_OFF     35651584                // 4 mirrors * 3 slots * 1024 u64 = 98304
#define FLAGSW_OFF   (RING_OFF + NMIR * RING_U64 * 8)   // 256 u32
#define FLAGSC_OFF   (FLAGSW_OFF + 1024)                // 256 u32
#define CALL_OFF     (FLAGSC_OFF + 1024)                // char_all (own line)
#define CTRL_BYTES   (NMIR * RING_U64 * 8 + 1024 + 1024 + 128)
#define WT2W_OFF     37748736                // 384*4096 float2 = 12582912 (ends 48 MiB)

typedef float f32x4 __attribute__((ext_vector_type(4)));

#define LD_AGENT(p) __hip_atomic_load((p), __ATOMIC_RELAXED, __HIP_MEMORY_SCOPE_AGENT)

static __device__ __forceinline__ float sigm(float x) { return 1.0f / (1.0f + __expf(-x)); }
static __device__ __forceinline__ float tanh_fast(float x) {
    float ax = fminf(fabsf(x), 15.0f);
    float e  = __expf(2.0f * ax);
    float t  = (e - 1.0f) / (e + 1.0f);
    return copysignf(t, x);
}

// ---------- prep: transposed k-major float2 pairs (separate dispatches) ----------
__global__ void prep_c_kernel(const float* __restrict__ Wih,
                              const float* __restrict__ Whh,
                              float2* __restrict__ WT2c) {
    int idx = blockIdx.x * blockDim.x + threadIdx.x;   // 256*1024
    if (idx >= 256 * GC) return;
    int kp = idx >> 10, row = idx & (GC - 1);
    int k = kp * 2;
    float2 v;
    if (k < CE) { v.x = Wih[row * CE + k];      v.y = Wih[row * CE + k + 1]; }
    else        { v.x = Whh[row * CE + k - CE]; v.y = Whh[row * CE + k - CE + 1]; }
    WT2c[idx] = v;
}

__global__ void prep_w_kernel(const float* __restrict__ Wih,
                              float2* __restrict__ WT2w) {
    int idx = blockIdx.x * blockDim.x + threadIdx.x;   // 384*4096
    if (idx >= 384 * GW) return;
    int kp = idx >> 12, row = idx & (GW - 1);
    float2 v;
    v.x = Wih[row * KW + 2 * kp];
    v.y = Wih[row * KW + 2 * kp + 1];
    WT2w[idx] = v;
}

// ---------- mega-kernel: char + wordin + rnn (v18) ----------
// v18 = v16 (proven best, 5.36 ms) with ONE change: multi-pass char.
//   char is now 64 blocks; block cb processes groups {cb, cb+64, cb+128,
//   cb+192} SEQUENTIALLY (low groups first). Pass 0 runs with only 64 blocks'
//   aggregate demand -> groups 0..63 finish near single-block latency
//   (~300 us) instead of v16's 256-block melee (~600 us), unblocking the rnn
//   ~300 us earlier. Later passes stay far ahead of the rnn's 17.6 us/group
//   consumption rate. No new dependency types (char still wait-free; wordin
//   waits flagsC[grp]; rnn waits flagsW — all proven patterns).
// v17's stagger + setprio are reverted (regressed: temporal spreading of
// wordin's WT2w stream doubled FETCH and lost L2 amortization).
__global__ void __launch_bounds__(512, 2) mega_kernel(
    const int* __restrict__ word_idxs,
    const int* __restrict__ char_idxs,
    const int* __restrict__ char_lens,
    const float* __restrict__ char_emb,       // [256][256]
    const float* __restrict__ word_emb,       // [50000][512]
    const float* __restrict__ bih_c,          // [1024]
    const float* __restrict__ bhh_c,          // [1024]
    const float* __restrict__ Whh_w,          // [4096][1024]
    const float* __restrict__ bih_w,          // [4096]
    const float* __restrict__ bhh_w,          // [4096]
    const float2* __restrict__ WT2c,          // [256][1024] k-pairs (in_gates tail)
    const float2* __restrict__ WT2w,          // [384][4096] k-pairs
    float* __restrict__ last,                 // [2048][256]
    float* __restrict__ in_gates,             // [2048][4096]
    unsigned long long* __restrict__ ring,    // [NMIR][3][1024] tagged h
    unsigned int* __restrict__ flagsW,        // [256] wordin-group done (==2)
    unsigned int* __restrict__ flagsC,        // [256] char-group done (==1)
    unsigned int* __restrict__ char_all,      // all-char counter (==256)
    float* __restrict__ out)                  // [2048][1024]
{
    __shared__ float smem[13312];             // 52 KB: max(char 52K, wordin 24K, rnn 8K)
    const int tid = threadIdx.x;

    if (blockIdx.x >= NWG_RNN + NWB_CHAR) {
        // ---------------- wordin producer role (exact v16) ----------------
        const int nb    = blockIdx.x - (NWG_RNN + NWB_CHAR);  // 0..511
        const int grp   = nb >> 1;               // 0..255: rows 8*grp..8*grp+8
        const int half  = nb & 1;
        const int jj    = tid & 255;
        const int gh    = tid >> 8;              // 0/1
        const int rb2   = half * 2 + gh;         // gate quarter 0..3
        const int wbase = grp * 8;
        float (*xh)[KW] = (float(*)[KW])smem;

        if (tid == 0) {
            while (LD_AGENT(flagsC + grp) < 1u) { __builtin_amdgcn_s_sleep(2); }
            if (grp >= 240)                      // writes in_gates rows >=1920 (WT2c alias)
                while (LD_AGENT(char_all) < 256u) { __builtin_amdgcn_s_sleep(2); }
        }
        __syncthreads();

        for (int w = 0; w < 8; w++) {
            int wi = word_idxs[wbase + w];
            xh[w][tid] = word_emb[(size_t)wi * WE + tid];
            if (tid < 256) xh[w][WE + tid] = last[(wbase + w) * CE + tid];
        }
        __syncthreads();

        float acc[4][8];
        #pragma unroll
        for (int g = 0; g < 4; g++)
            #pragma unroll
            for (int w = 0; w < 8; w++) acc[g][w] = 0.0f;

        for (int kp = 0; kp < KW / 2; kp++) {    // 384 pairs
            float2 wv[4];
            #pragma unroll
            for (int g = 0; g < 4; g++) wv[g] = WT2w[(size_t)kp * GW + rb2 * GC + g * CE + jj];
            #pragma unroll
            for (int w = 0; w < 8; w++) {
                float2 xv = *(const float2*)&xh[w][2 * kp];
                #pragma unroll
                for (int g = 0; g < 4; g++)
                    acc[g][w] = fmaf(wv[g].y, xv.y, fmaf(wv[g].x, xv.x, acc[g][w]));
            }
        }

        #pragma unroll
        for (int g = 0; g < 4; g++) {
            int row = rb2 * GC + g * CE + jj;
            float bias = bih_w[row] + bhh_w[row];
            #pragma unroll
            for (int w = 0; w < 8; w++)
                __hip_atomic_store(in_gates + (size_t)(wbase + w) * GW + row,
                                   acc[g][w] + bias,
                                   __ATOMIC_RELAXED, __HIP_MEMORY_SCOPE_AGENT);
        }
        __syncthreads();   // drains vmcnt -> all stores retired
        if (tid == 0)
            __hip_atomic_fetch_add(flagsW + grp, 1u,
                                   __ATOMIC_RELEASE, __HIP_MEMORY_SCOPE_AGENT);
        return;
    }

    if (blockIdx.x >= NWG_RNN) {
        // ------------- char producer role: 4 sequential groups, low first -------------
        const int cbase = blockIdx.x - NWG_RNN;  // 0..63
        const int j = tid & 255;                 // unit
        const int p = tid >> 8;                  // 0/1: gate rows 2p, 2p+1
        float (*cxh)[2 * CE]  = (float(*)[2 * CE])smem;                 // [8][512] 16 KB
        float (*cgex)[256][9] = (float(*)[256][9])(smem + 8 * 2 * CE);  // [4][256][9] 36 KB

        const float bias0 = bih_c[(2 * p) * CE + j]     + bhh_c[(2 * p) * CE + j];
        const float bias1 = bih_c[(2 * p + 1) * CE + j] + bhh_c[(2 * p + 1) * CE + j];
        const float2* __restrict__ wrow0 = WT2c + (2 * p) * CE + j;
        const float2* __restrict__ wrow1 = WT2c + (2 * p + 1) * CE + j;

        for (int pass = 0; pass < NPASS; pass++) {
            const int cb = pass * NWB_CHAR + cbase;  // group id: pass 0 = groups 0..63
            const int wbase = cb * 8;

            int len[4];
            float c[4] = {0.f, 0.f, 0.f, 0.f};   // c-state for words 4p..4p+3
            #pragma unroll
            for (int ww = 0; ww < 4; ww++) len[ww] = char_lens[wbase + 4 * p + ww];
            int tmax = 1;
            #pragma unroll
            for (int w = 0; w < 8; w++) {
                int lw = char_lens[wbase + w];
                tmax = lw > tmax ? lw : tmax;
            }
            #pragma unroll
            for (int ww = 0; ww < 4; ww++) cxh[4 * p + ww][CE + j] = 0.0f;  // h_{-1}=0

            for (int t = 0; t < tmax; t++) {
                #pragma unroll
                for (int ww = 0; ww < 4; ww++) {
                    int w = 4 * p + ww;
                    int ci = char_idxs[(wbase + w) * LMAX + t];
                    cxh[w][j] = char_emb[ci * CE + j];
                }
                __syncthreads();                 // B1: x(t) + h(t-1) visible

                float a0[8], a1[8];
                #pragma unroll
                for (int w = 0; w < 8; w++) { a0[w] = 0.0f; a1[w] = 0.0f; }

                #pragma unroll 2
                for (int kp = 0; kp < CE; kp++) {
                    float2 wv0 = wrow0[(size_t)kp * GC];
                    float2 wv1 = wrow1[(size_t)kp * GC];
                    #pragma unroll
                    for (int w = 0; w < 8; w++) {
                        float2 xv = *(const float2*)&cxh[w][2 * kp];   // broadcast
                        a0[w] = fmaf(wv0.y, xv.y, fmaf(wv0.x, xv.x, a0[w]));
                        a1[w] = fmaf(wv1.y, xv.y, fmaf(wv1.x, xv.x, a1[w]));
                    }
                }

                #pragma unroll
                for (int w = 0; w < 8; w++) {
                    cgex[2 * p][j][w]     = a0[w] + bias0;
                    cgex[2 * p + 1][j][w] = a1[w] + bias1;
                }
                __syncthreads();                 // B2: gex ready; all cxh reads done

                #pragma unroll
                for (int ww = 0; ww < 4; ww++) {
                    int w = 4 * p + ww;
                    float gi = cgex[0][j][w];
                    float gf = cgex[1][j][w];
                    float gg = cgex[2][j][w];
                    float go = cgex[3][j][w];
                    float iv = sigm(gi);
                    float fv = sigm(gf);
                    float gv = tanhf(gg);
                    float ov = sigm(go);
                    c[ww] = fv * c[ww] + iv * gv;
                    float h = ov * tanhf(c[ww]);
                    cxh[w][CE + j] = h;          // read by FMA(t+1) after B1(t+1)
                    if (t == len[ww] - 1)
                        __hip_atomic_store(last + (wbase + w) * CE + j, h,
                                           __ATOMIC_RELAXED, __HIP_MEMORY_SCOPE_AGENT);
                }
            }

            __syncthreads();                     // drains vmcnt; all reads of this
                                                 // pass's cxh/cgex complete
            if (tid == 0) {
                __hip_atomic_fetch_add(flagsC + cb, 1u,
                                       __ATOMIC_RELEASE, __HIP_MEMORY_SCOPE_AGENT);
                __hip_atomic_fetch_add(char_all, 1u,
                                       __ATOMIC_RELEASE, __HIP_MEMORY_SCOPE_AGENT);
            }
            // next pass re-zeroes h_{-1} and restarts; barrier above ordered it
        }
        return;
    }

    // ---------------- recurrence role (EXACT v9) ----------------
    const int v = tid >> 6;                   // wave 0..7
    const int l = tid & 63;
    const int unit = blockIdx.x * 8 + v;
    float (*hbb)[HDIM] = (float(*)[HDIM])smem;   // [2][1024] in first 8 KB
    const unsigned long long* ring_my = ring + (size_t)(blockIdx.x & (NMIR - 1)) * RING_U64;

    // resident weights: all 4 gates of this wave's unit, full K
    f32x4 w[4][4];
    #pragma unroll
    for (int g = 0; g < 4; g++)
        #pragma unroll
        for (int cc = 0; cc < 4; cc++)
            w[g][cc] = *(const f32x4*)(Whh_w + (size_t)(g * HDIM + unit) * HDIM
                                       + cc * 256 + l * 4);
    #pragma unroll
    for (int g = 0; g < 4; g++)
        #pragma unroll
        for (int cc = 0; cc < 4; cc++)
            asm volatile("" : "+v"(w[g][cc]));

    float c_reg = 0.0f;                       // maintained identically on lanes 0..3

    for (int t = 0; t < S_WORDS; t++) {
        if ((t & 7) == 0) {
            const unsigned int* fl = flagsW + (t >> 3);
            while (LD_AGENT(fl) < 2u) { __builtin_amdgcn_s_sleep(8); }
        }

        float ing0 = 0.f, ing1 = 0.f, ing2 = 0.f, ing3 = 0.f;
        if (l < 4) {
            const float* ig = in_gates + (size_t)t * GW + unit;
            ing0 = LD_AGENT(ig + 0 * HDIM);
            ing1 = LD_AGENT(ig + 1 * HDIM);
            ing2 = LD_AGENT(ig + 2 * HDIM);
            ing3 = LD_AGENT(ig + 3 * HDIM);
        }

        // incremental depth-1 poll of this wave's 128-entry slice of our mirror
        const unsigned long long* slot = ring_my + (size_t)(t % 3) * HDIM + v * 128;
        unsigned long long a0 = 0, a1 = 0;
        bool ok0 = false, ok1 = false;
        do {
            if (!ok0) {
                a0 = LD_AGENT(slot + l);
                ok0 = ((unsigned)(a0 >> 32) == (unsigned)t);
            }
            if (!ok1) {
                a1 = LD_AGENT(slot + 64 + l);
                ok1 = ((unsigned)(a1 >> 32) == (unsigned)t);
            }
        } while (!__all(ok0 && ok1));
        {
            union { unsigned u32; float f; } c0, c1;
            c0.u32 = (unsigned)a0; c1.u32 = (unsigned)a1;
            hbb[t & 1][v * 128 + l]      = c0.f;
            hbb[t & 1][v * 128 + 64 + l] = c1.f;
        }
        __syncthreads();                      // single barrier per step

        float acc0 = 0.f, acc1 = 0.f, acc2 = 0.f, acc3 = 0.f;
        const float* hb = hbb[t & 1];
        #pragma unroll
        for (int cc = 0; cc < 4; cc++) {
            f32x4 hv = *(const f32x4*)&hb[cc * 256 + l * 4];
            #pragma unroll
            for (int e = 0; e < 4; e++) {
                acc0 = fmaf(w[0][cc][e], hv[e], acc0);
                acc1 = fmaf(w[1][cc][e], hv[e], acc1);
                acc2 = fmaf(w[2][cc][e], hv[e], acc2);
                acc3 = fmaf(w[3][cc][e], hv[e], acc3);
            }
        }
        #pragma unroll
        for (int off = 32; off >= 1; off >>= 1) {   // butterfly allreduce
            acc0 += __shfl_xor(acc0, off, 64);
            acc1 += __shfl_xor(acc1, off, 64);
            acc2 += __shfl_xor(acc2, off, 64);
            acc3 += __shfl_xor(acc3, off, 64);
        }

        if (l < 4) {                          // redundant elementwise on lanes 0..3
            float iv = sigm(acc0 + ing0);
            float fv = sigm(acc1 + ing1);
            float gv = tanh_fast(acc2 + ing2);
            float ov = sigm(acc3 + ing3);
            c_reg = fv * c_reg + iv * gv;
            float h = ov * tanh_fast(c_reg);
            union { float f; unsigned u32; } cv; cv.f = h;
            unsigned long long pv =
                ((unsigned long long)(unsigned)(t + 1) << 32) | (unsigned long long)cv.u32;
            __hip_atomic_store(ring + (size_t)l * RING_U64
                                    + (size_t)((t + 1) % 3) * HDIM + unit, pv,
                               __ATOMIC_RELAXED, __HIP_MEMORY_SCOPE_AGENT);
            if (l == 0) out[(size_t)t * HDIM + unit] = h;
        }
        // No trailing barrier: hbb double-buffered (v9 transitive argument).
    }
}

extern "C" void kernel_launch(void* const* d_in, const int* in_sizes, int n_in,
                              void* d_out, int out_size, void* d_ws, size_t ws_size,
                              hipStream_t stream) {
    const int* word_idxs = (const int*)d_in[0];
    const int* char_idxs = (const int*)d_in[1];
    const int* char_lens = (const int*)d_in[2];
    const float* char_emb = (const float*)d_in[3];
    const float* word_emb = (const float*)d_in[4];
    const float* Wih_c = (const float*)d_in[5];
    const float* Whh_c = (const float*)d_in[6];
    const float* bih_c = (const float*)d_in[7];
    const float* bhh_c = (const float*)d_in[8];
    const float* Wih_w = (const float*)d_in[9];
    const float* Whh_w = (const float*)d_in[10];
    const float* bih_w = (const float*)d_in[11];
    const float* bhh_w = (const float*)d_in[12];

    char* ws = (char*)d_ws;
    float*  in_gates = (float*)(ws + IN_GATES_OFF);
    float2* WT2c     = (float2*)(ws + WT2C_OFF);
    float*  last     = (float*)(ws + LAST_OFF);
    float2* WT2w     = (float2*)(ws + WT2W_OFF);
    unsigned long long* ring = (unsigned long long*)(ws + RING_OFF);
    unsigned int* flagsW     = (unsigned int*)(ws + FLAGSW_OFF);
    unsigned int* flagsC     = (unsigned int*)(ws + FLAGSC_OFF);
    unsigned int* char_all   = (unsigned int*)(ws + CALL_OFF);

    // weight transposes: stream-ordered BEFORE the mega kernel (visibility via
    // kernel-boundary release/acquire)
    hipLaunchKernelGGL(prep_c_kernel, dim3(1024), dim3(256), 0, stream,
                       Wih_c, Whh_c, WT2c);
    hipLaunchKernelGGL(prep_w_kernel, dim3(6144), dim3(256), 0, stream,
                       Wih_w, WT2w);
    // zero ring (slot0 tag=0 = valid t=0 h=0) + flagsW + flagsC + char_all
    hipMemsetAsync(ws + RING_OFF, 0, CTRL_BYTES, stream);
    hipLaunchKernelGGL(mega_kernel, dim3(NWG_RNN + NWB_CHAR + NWB_WIN), dim3(512),
                       0, stream,
                       word_idxs, char_idxs, char_lens, char_emb, word_emb,
                       bih_c, bhh_c, Whh_w, bih_w, bhh_w,
                       WT2c, WT2w, last, in_gates,
                       ring, flagsW, flagsC, char_all, (float*)d_out);
}

// Round 13
// 5367.428 us; speedup vs baseline: 1.0746x; 1.0746x over previous
//
#include <hip/hip_runtime.h>
#include <stdint.h>

// Problem constants (from reference)
#define S_WORDS 2048
#define LMAX    16
#define CE      256
#define WE      512
#define HDIM    1024
#define GC      1024   // 4*CE
#define GW      4096   // 4*HDIM
#define KW      768    // WE + CE
#define NWG_RNN  128   // recurrence WGs: 8 units each, 1 unit per wave
#define NWB_CHAR 256   // char producer blocks (8 words each == 1 wordin group)
#define NWB_WIN  512   // wordin producer blocks (2 per 8-row group)
#define NMIR    4      // ring mirrors
#define RING_U64 (3 * HDIM)   // u64 per mirror (3 slots x 1024)

// Workspace layout (bytes) — high-water 50,331,648 (48 MiB).
// WT2c aliases in_gates rows 1920..2047 (2 MiB tail). Writers of those rows
// are wordin groups 240..255 only, and they gate on char_all==256. Ring +
// flags live in the old WT2c region. prep_c/prep_w run as PRIOR dispatches
// -> weight visibility via kernel-boundary ordering.
#define IN_GATES_OFF 0                       // 2048*4096 fp32 = 33554432
#define WT2C_OFF     31457280                // in_gates rows 1920.. (gated alias)
#define LAST_OFF     33554432                // 2048*256 fp32 = 2097152
#define RING_OFF     35651584                // 4 mirrors * 3 slots * 1024 u64 = 98304
#define FLAGSW_OFF   (RING_OFF + NMIR * RING_U64 * 8)   // 256 u32
#define FLAGSC_OFF   (FLAGSW_OFF + 1024)                // 256 u32
#define CALL_OFF     (FLAGSC_OFF + 1024)                // char_all (own line)
#define CTRL_BYTES   (NMIR * RING_U64 * 8 + 1024 + 1024 + 128)
#define WT2W_OFF     37748736                // 384*4096 float2 = 12582912 (ends 48 MiB)

typedef float f32x4 __attribute__((ext_vector_type(4)));

#define LD_AGENT(p) __hip_atomic_load((p), __ATOMIC_RELAXED, __HIP_MEMORY_SCOPE_AGENT)

static __device__ __forceinline__ float sigm(float x) { return 1.0f / (1.0f + __expf(-x)); }
// fast tanh: (e^{2|x|}-1)/(e^{2|x|}+1) with sign restore; clamp avoids inf/inf.
// Validated in the 2048-step recurrence since v0 (absmax stable at 2.44e-4);
// v19 also uses it in the char melee (VALU-bound phase, libm tanhf ~10x cost).
static __device__ __forceinline__ float tanh_fast(float x) {
    float ax = fminf(fabsf(x), 15.0f);
    float e  = __expf(2.0f * ax);
    float t  = (e - 1.0f) / (e + 1.0f);
    return copysignf(t, x);
}

// ---------- prep: transposed k-major float2 pairs (separate dispatches) ----------
__global__ void prep_c_kernel(const float* __restrict__ Wih,
                              const float* __restrict__ Whh,
                              float2* __restrict__ WT2c) {
    int idx = blockIdx.x * blockDim.x + threadIdx.x;   // 256*1024
    if (idx >= 256 * GC) return;
    int kp = idx >> 10, row = idx & (GC - 1);
    int k = kp * 2;
    float2 v;
    if (k < CE) { v.x = Wih[row * CE + k];      v.y = Wih[row * CE + k + 1]; }
    else        { v.x = Whh[row * CE + k - CE]; v.y = Whh[row * CE + k - CE + 1]; }
    WT2c[idx] = v;
}

__global__ void prep_w_kernel(const float* __restrict__ Wih,
                              float2* __restrict__ WT2w) {
    int idx = blockIdx.x * blockDim.x + threadIdx.x;   // 384*4096
    if (idx >= 384 * GW) return;
    int kp = idx >> 12, row = idx & (GW - 1);
    float2 v;
    v.x = Wih[row * KW + 2 * kp];
    v.y = Wih[row * KW + 2 * kp + 1];
    WT2w[idx] = v;
}

// ---------- mega-kernel: char + wordin + rnn (v19 = v16 + tanh_fast in char) ----------
// v16 structure (proven best, 5.36 ms): all producers launch at once —
// concentrated execution maximizes WT2w L2 amortization (v17 stagger and v18
// multi-pass both regressed by spreading wordin's weight stream over time,
// FETCH 0.6 -> 1.1-1.3 GB). Roles by blockIdx:
//   rnn    0..127:   exact v9 recurrence; waits flagsW
//   char   128..383: gate-split char LSTM, 8 words/block, NO waits
//   wordin 384..895: waits flagsC[grp]==1; grp>=240 also waits char_all==256
//                    before overwriting the WT2c alias region
__global__ void __launch_bounds__(512, 2) mega_kernel(
    const int* __restrict__ word_idxs,
    const int* __restrict__ char_idxs,
    const int* __restrict__ char_lens,
    const float* __restrict__ char_emb,       // [256][256]
    const float* __restrict__ word_emb,       // [50000][512]
    const float* __restrict__ bih_c,          // [1024]
    const float* __restrict__ bhh_c,          // [1024]
    const float* __restrict__ Whh_w,          // [4096][1024]
    const float* __restrict__ bih_w,          // [4096]
    const float* __restrict__ bhh_w,          // [4096]
    const float2* __restrict__ WT2c,          // [256][1024] k-pairs (in_gates tail)
    const float2* __restrict__ WT2w,          // [384][4096] k-pairs
    float* __restrict__ last,                 // [2048][256]
    float* __restrict__ in_gates,             // [2048][4096]
    unsigned long long* __restrict__ ring,    // [NMIR][3][1024] tagged h
    unsigned int* __restrict__ flagsW,        // [256] wordin-group done (==2)
    unsigned int* __restrict__ flagsC,        // [256] char-group done (==1)
    unsigned int* __restrict__ char_all,      // all-char counter (==256)
    float* __restrict__ out)                  // [2048][1024]
{
    __shared__ float smem[13312];             // 52 KB: max(char 52K, wordin 24K, rnn 8K)
    const int tid = threadIdx.x;

    if (blockIdx.x >= NWG_RNN + NWB_CHAR) {
        // ---------------- wordin producer role ----------------
        const int nb    = blockIdx.x - (NWG_RNN + NWB_CHAR);  // 0..511
        const int grp   = nb >> 1;               // 0..255: rows 8*grp..8*grp+8
        const int half  = nb & 1;
        const int jj    = tid & 255;
        const int gh    = tid >> 8;              // 0/1
        const int rb2   = half * 2 + gh;         // gate quarter 0..3
        const int wbase = grp * 8;
        float (*xh)[KW] = (float(*)[KW])smem;

        if (tid == 0) {
            while (LD_AGENT(flagsC + grp) < 1u) { __builtin_amdgcn_s_sleep(2); }
            if (grp >= 240)                      // writes in_gates rows >=1920 (WT2c alias)
                while (LD_AGENT(char_all) < (unsigned)NWB_CHAR) { __builtin_amdgcn_s_sleep(2); }
        }
        __syncthreads();

        for (int w = 0; w < 8; w++) {
            int wi = word_idxs[wbase + w];
            xh[w][tid] = word_emb[(size_t)wi * WE + tid];
            if (tid < 256) xh[w][WE + tid] = last[(wbase + w) * CE + tid];
        }
        __syncthreads();

        float acc[4][8];
        #pragma unroll
        for (int g = 0; g < 4; g++)
            #pragma unroll
            for (int w = 0; w < 8; w++) acc[g][w] = 0.0f;

        for (int kp = 0; kp < KW / 2; kp++) {    // 384 pairs
            float2 wv[4];
            #pragma unroll
            for (int g = 0; g < 4; g++) wv[g] = WT2w[(size_t)kp * GW + rb2 * GC + g * CE + jj];
            #pragma unroll
            for (int w = 0; w < 8; w++) {
                float2 xv = *(const float2*)&xh[w][2 * kp];
                #pragma unroll
                for (int g = 0; g < 4; g++)
                    acc[g][w] = fmaf(wv[g].y, xv.y, fmaf(wv[g].x, xv.x, acc[g][w]));
            }
        }

        #pragma unroll
        for (int g = 0; g < 4; g++) {
            int row = rb2 * GC + g * CE + jj;
            float bias = bih_w[row] + bhh_w[row];
            #pragma unroll
            for (int w = 0; w < 8; w++)
                __hip_atomic_store(in_gates + (size_t)(wbase + w) * GW + row,
                                   acc[g][w] + bias,
                                   __ATOMIC_RELAXED, __HIP_MEMORY_SCOPE_AGENT);
        }
        __syncthreads();   // drains vmcnt -> all stores retired
        if (tid == 0)
            __hip_atomic_fetch_add(flagsW + grp, 1u,
                                   __ATOMIC_RELEASE, __HIP_MEMORY_SCOPE_AGENT);
        return;
    }

    if (blockIdx.x >= NWG_RNN) {
        // ---------------- char producer role (gate-split, 8 words, no waits) --------
        const int cb = blockIdx.x - NWG_RNN;     // 0..255 == wordin group id
        const int wbase = cb * 8;
        const int j = tid & 255;                 // unit
        const int p = tid >> 8;                  // 0/1: gate rows 2p, 2p+1
        float (*cxh)[2 * CE]  = (float(*)[2 * CE])smem;                 // [8][512] 16 KB
        float (*cgex)[256][9] = (float(*)[256][9])(smem + 8 * 2 * CE);  // [4][256][9] 36 KB

        const float bias0 = bih_c[(2 * p) * CE + j]     + bhh_c[(2 * p) * CE + j];
        const float bias1 = bih_c[(2 * p + 1) * CE + j] + bhh_c[(2 * p + 1) * CE + j];

        int len[4];
        float c[4] = {0.f, 0.f, 0.f, 0.f};       // c-state for words 4p..4p+3
        #pragma unroll
        for (int ww = 0; ww < 4; ww++) len[ww] = char_lens[wbase + 4 * p + ww];
        int tmax = 1;
        #pragma unroll
        for (int w = 0; w < 8; w++) {
            int lw = char_lens[wbase + w];
            tmax = lw > tmax ? lw : tmax;
        }
        #pragma unroll
        for (int ww = 0; ww < 4; ww++) cxh[4 * p + ww][CE + j] = 0.0f;   // h_{-1}=0

        const float2* __restrict__ wrow0 = WT2c + (2 * p) * CE + j;
        const float2* __restrict__ wrow1 = WT2c + (2 * p + 1) * CE + j;

        for (int t = 0; t < tmax; t++) {
            #pragma unroll
            for (int ww = 0; ww < 4; ww++) {
                int w = 4 * p + ww;
                int ci = char_idxs[(wbase + w) * LMAX + t];
                cxh[w][j] = char_emb[ci * CE + j];
            }
            __syncthreads();                     // B1: x(t) + h(t-1) visible

            float a0[8], a1[8];
            #pragma unroll
            for (int w = 0; w < 8; w++) { a0[w] = 0.0f; a1[w] = 0.0f; }

            #pragma unroll 2
            for (int kp = 0; kp < CE; kp++) {
                float2 wv0 = wrow0[(size_t)kp * GC];
                float2 wv1 = wrow1[(size_t)kp * GC];
                #pragma unroll
                for (int w = 0; w < 8; w++) {
                    float2 xv = *(const float2*)&cxh[w][2 * kp];   // broadcast
                    a0[w] = fmaf(wv0.y, xv.y, fmaf(wv0.x, xv.x, a0[w]));
                    a1[w] = fmaf(wv1.y, xv.y, fmaf(wv1.x, xv.x, a1[w]));
                }
            }

            #pragma unroll
            for (int w = 0; w < 8; w++) {
                cgex[2 * p][j][w]     = a0[w] + bias0;
                cgex[2 * p + 1][j][w] = a1[w] + bias1;
            }
            __syncthreads();                     // B2: gex ready; all cxh reads done

            #pragma unroll
            for (int ww = 0; ww < 4; ww++) {
                int w = 4 * p + ww;
                float gi = cgex[0][j][w];
                float gf = cgex[1][j][w];
                float gg = cgex[2][j][w];
                float go = cgex[3][j][w];
                float iv = sigm(gi);
                float fv = sigm(gf);
                float gv = tanh_fast(gg);        // v19: was libm tanhf
                float ov = sigm(go);
                c[ww] = fv * c[ww] + iv * gv;
                float h = ov * tanh_fast(c[ww]); // v19: was libm tanhf
                cxh[w][CE + j] = h;              // read by FMA(t+1) after B1(t+1)
                if (t == len[ww] - 1)
                    __hip_atomic_store(last + (wbase + w) * CE + j, h,
                                       __ATOMIC_RELAXED, __HIP_MEMORY_SCOPE_AGENT);
            }
        }

        __syncthreads();                         // drains vmcnt (last stores retired)
        if (tid == 0) {
            __hip_atomic_fetch_add(flagsC + cb, 1u,
                                   __ATOMIC_RELEASE, __HIP_MEMORY_SCOPE_AGENT);
            __hip_atomic_fetch_add(char_all, 1u,
                                   __ATOMIC_RELEASE, __HIP_MEMORY_SCOPE_AGENT);
        }
        return;
    }

    // ---------------- recurrence role (EXACT v9) ----------------
    const int v = tid >> 6;                   // wave 0..7
    const int l = tid & 63;
    const int unit = blockIdx.x * 8 + v;
    float (*hbb)[HDIM] = (float(*)[HDIM])smem;   // [2][1024] in first 8 KB
    const unsigned long long* ring_my = ring + (size_t)(blockIdx.x & (NMIR - 1)) * RING_U64;

    // resident weights: all 4 gates of this wave's unit, full K
    f32x4 w[4][4];
    #pragma unroll
    for (int g = 0; g < 4; g++)
        #pragma unroll
        for (int cc = 0; cc < 4; cc++)
            w[g][cc] = *(const f32x4*)(Whh_w + (size_t)(g * HDIM + unit) * HDIM
                                       + cc * 256 + l * 4);
    #pragma unroll
    for (int g = 0; g < 4; g++)
        #pragma unroll
        for (int cc = 0; cc < 4; cc++)
            asm volatile("" : "+v"(w[g][cc]));

    float c_reg = 0.0f;                       // maintained identically on lanes 0..3

    for (int t = 0; t < S_WORDS; t++) {
        if ((t & 7) == 0) {
            const unsigned int* fl = flagsW + (t >> 3);
            while (LD_AGENT(fl) < 2u) { __builtin_amdgcn_s_sleep(8); }
        }

        float ing0 = 0.f, ing1 = 0.f, ing2 = 0.f, ing3 = 0.f;
        if (l < 4) {
            const float* ig = in_gates + (size_t)t * GW + unit;
            ing0 = LD_AGENT(ig + 0 * HDIM);
            ing1 = LD_AGENT(ig + 1 * HDIM);
            ing2 = LD_AGENT(ig + 2 * HDIM);
            ing3 = LD_AGENT(ig + 3 * HDIM);
        }

        // incremental depth-1 poll of this wave's 128-entry slice of our mirror
        const unsigned long long* slot = ring_my + (size_t)(t % 3) * HDIM + v * 128;
        unsigned long long a0 = 0, a1 = 0;
        bool ok0 = false, ok1 = false;
        do {
            if (!ok0) {
                a0 = LD_AGENT(slot + l);
                ok0 = ((unsigned)(a0 >> 32) == (unsigned)t);
            }
            if (!ok1) {
                a1 = LD_AGENT(slot + 64 + l);
                ok1 = ((unsigned)(a1 >> 32) == (unsigned)t);
            }
        } while (!__all(ok0 && ok1));
        {
            union { unsigned u32; float f; } c0, c1;
            c0.u32 = (unsigned)a0; c1.u32 = (unsigned)a1;
            hbb[t & 1][v * 128 + l]      = c0.f;
            hbb[t & 1][v * 128 + 64 + l] = c1.f;
        }
        __syncthreads();                      // single barrier per step

        float acc0 = 0.f, acc1 = 0.f, acc2 = 0.f, acc3 = 0.f;
        const float* hb = hbb[t & 1];
        #pragma unroll
        for (int cc = 0; cc < 4; cc++) {
            f32x4 hv = *(const f32x4*)&hb[cc * 256 + l * 4];
            #pragma unroll
            for (int e = 0; e < 4; e++) {
                acc0 = fmaf(w[0][cc][e], hv[e], acc0);
                acc1 = fmaf(w[1][cc][e], hv[e], acc1);
                acc2 = fmaf(w[2][cc][e], hv[e], acc2);
                acc3 = fmaf(w[3][cc][e], hv[e], acc3);
            }
        }
        #pragma unroll
        for (int off = 32; off >= 1; off >>= 1) {   // butterfly allreduce
            acc0 += __shfl_xor(acc0, off, 64);
            acc1 += __shfl_xor(acc1, off, 64);
            acc2 += __shfl_xor(acc2, off, 64);
            acc3 += __shfl_xor(acc3, off, 64);
        }

        if (l < 4) {                          // redundant elementwise on lanes 0..3
            float iv = sigm(acc0 + ing0);
            float fv = sigm(acc1 + ing1);
            float gv = tanh_fast(acc2 + ing2);
            float ov = sigm(acc3 + ing3);
            c_reg = fv * c_reg + iv * gv;
            float h = ov * tanh_fast(c_reg);
            union { float f; unsigned u32; } cv; cv.f = h;
            unsigned long long pv =
                ((unsigned long long)(unsigned)(t + 1) << 32) | (unsigned long long)cv.u32;
            __hip_atomic_store(ring + (size_t)l * RING_U64
                                    + (size_t)((t + 1) % 3) * HDIM + unit, pv,
                               __ATOMIC_RELAXED, __HIP_MEMORY_SCOPE_AGENT);
            if (l == 0) out[(size_t)t * HDIM + unit] = h;
        }
        // No trailing barrier: hbb double-buffered (v9 transitive argument).
    }
}

extern "C" void kernel_launch(void* const* d_in, const int* in_sizes, int n_in,
                              void* d_out, int out_size, void* d_ws, size_t ws_size,
                              hipStream_t stream) {
    const int* word_idxs = (const int*)d_in[0];
    const int* char_idxs = (const int*)d_in[1];
    const int* char_lens = (const int*)d_in[2];
    const float* char_emb = (const float*)d_in[3];
    const float* word_emb = (const float*)d_in[4];
    const float* Wih_c = (const float*)d_in[5];
    const float* Whh_c = (const float*)d_in[6];
    const float* bih_c = (const float*)d_in[7];
    const float* bhh_c = (const float*)d_in[8];
    const float* Wih_w = (const float*)d_in[9];
    const float* Whh_w = (const float*)d_in[10];
    const float* bih_w = (const float*)d_in[11];
    const float* bhh_w = (const float*)d_in[12];

    char* ws = (char*)d_ws;
    float*  in_gates = (float*)(ws + IN_GATES_OFF);
    float2* WT2c     = (float2*)(ws + WT2C_OFF);
    float*  last     = (float*)(ws + LAST_OFF);
    float2* WT2w     = (float2*)(ws + WT2W_OFF);
    unsigned long long* ring = (unsigned long long*)(ws + RING_OFF);
    unsigned int* flagsW     = (unsigned int*)(ws + FLAGSW_OFF);
    unsigned int* flagsC     = (unsigned int*)(ws + FLAGSC_OFF);
    unsigned int* char_all   = (unsigned int*)(ws + CALL_OFF);

    // weight transposes: stream-ordered BEFORE the mega kernel (visibility via
    // kernel-boundary release/acquire)
    hipLaunchKernelGGL(prep_c_kernel, dim3(1024), dim3(256), 0, stream,
                       Wih_c, Whh_c, WT2c);
    hipLaunchKernelGGL(prep_w_kernel, dim3(6144), dim3(256), 0, stream,
                       Wih_w, WT2w);
    // zero ring (slot0 tag=0 = valid t=0 h=0) + flagsW + flagsC + char_all
    hipMemsetAsync(ws + RING_OFF, 0, CTRL_BYTES, stream);
    hipLaunchKernelGGL(mega_kernel, dim3(NWG_RNN + NWB_CHAR + NWB_WIN), dim3(512),
                       0, stream,
                       word_idxs, char_idxs, char_lens, char_emb, word_emb,
                       bih_c, bhh_c, Whh_w, bih_w, bhh_w,
                       WT2c, WT2w, last, in_gates,
                       ring, flagsW, flagsC, char_all, (float*)d_out);
}